// Round 1
// baseline (4622.207 us; speedup 1.0000x reference)
//
#include <hip/hip_runtime.h>
#include <float.h>
#include <math.h>

#define NQ 2048
#define NT 100000
#define DIM 512
#define KTOP 5
#define NCHUNK 32
#define CHUNK 3125      // NT / NCHUNK
#define QT 64           // queries per block
#define TT 64           // targets per tile
#define BK 32           // k-slice
#define NTILES 49       // ceil(CHUNK/TT)
#define LDA 36          // padded LDS row stride (multiple of 4, odd multiple of 4 mod 8)

__device__ __forceinline__ bool lt_pair(float v1, int i1, float v2, int i2) {
  return v1 < v2 || (v1 == v2 && i1 < i2);
}

// ---------------- norms: t2[NT], x2[NQ] ----------------
__global__ __launch_bounds__(256) void norms_kernel(
    const float* __restrict__ x, const float* __restrict__ T,
    float* __restrict__ t2, float* __restrict__ x2) {
  int gid = blockIdx.x * 256 + threadIdx.x;
  int wave = gid >> 6;
  int lane = threadIdx.x & 63;
  if (wave >= NT + NQ) return;
  const float* row = (wave < NT) ? (T + (size_t)wave * DIM)
                                 : (x + (size_t)(wave - NT) * DIM);
  const float4* r4 = (const float4*)row;
  float4 a = r4[lane];
  float4 b = r4[lane + 64];
  float s = a.x*a.x + a.y*a.y + a.z*a.z + a.w*a.w
          + b.x*b.x + b.y*b.y + b.z*b.z + b.w*b.w;
#pragma unroll
  for (int off = 32; off > 0; off >>= 1) s += __shfl_down(s, off, 64);
  if (lane == 0) { if (wave < NT) t2[wave] = s; else x2[wave - NT] = s; }
}

// ---------------- main: fused GEMM + top-5 per (qtile, chunk) ----------------
__global__ __launch_bounds__(256) void knn_main(
    const float* __restrict__ x, const float* __restrict__ T,
    const float* __restrict__ t2g,
    float* __restrict__ pvals, int* __restrict__ pidx) {
  __shared__ float smem[2 * QT * LDA];   // As[64][36] + Bs[64][36]
  float* As = smem;
  float* Bs = smem + QT * LDA;

  const int tid = threadIdx.x;
  const int tx = tid & 15;        // target group
  const int ty = tid >> 4;        // query group
  const int q0 = blockIdx.x * QT;
  const int cbase = blockIdx.y * CHUNK;
  const int cend = cbase + CHUNK;

  float tv[4][KTOP];
  int   ti[4][KTOP];
#pragma unroll
  for (int i = 0; i < 4; ++i)
#pragma unroll
    for (int s = 0; s < KTOP; ++s) { tv[i][s] = FLT_MAX; ti[i][s] = 0x7FFFFFFF; }

  for (int tt = 0; tt < NTILES; ++tt) {
    const int jbase = cbase + tt * TT;
    float acc[4][4];
#pragma unroll
    for (int i = 0; i < 4; ++i)
#pragma unroll
      for (int j = 0; j < 4; ++j) acc[i][j] = 0.f;

    for (int kb = 0; kb < DIM; kb += BK) {
      // stage A (x tile) and B (T tile): 64 rows x 32 floats each
#pragma unroll
      for (int r = 0; r < 2; ++r) {
        int l2 = tid + r * 256;
        int row = l2 >> 3;
        int c4 = (l2 & 7) << 2;
        float4 av = *(const float4*)(x + (size_t)(q0 + row) * DIM + kb + c4);
        *(float4*)(As + row * LDA + c4) = av;
        int jr = jbase + row; jr = jr < NT - 1 ? jr : NT - 1;
        float4 bv = *(const float4*)(T + (size_t)jr * DIM + kb + c4);
        *(float4*)(Bs + row * LDA + c4) = bv;
      }
      __syncthreads();
#pragma unroll
      for (int kk = 0; kk < BK; kk += 4) {
        float4 af[4], bf[4];
#pragma unroll
        for (int i = 0; i < 4; ++i)
          af[i] = *(const float4*)(As + (ty + 16 * i) * LDA + kk);
#pragma unroll
        for (int j = 0; j < 4; ++j)
          bf[j] = *(const float4*)(Bs + (tx + 16 * j) * LDA + kk);
#pragma unroll
        for (int i = 0; i < 4; ++i)
#pragma unroll
          for (int j = 0; j < 4; ++j) {
            acc[i][j] = fmaf(af[i].x, bf[j].x, acc[i][j]);
            acc[i][j] = fmaf(af[i].y, bf[j].y, acc[i][j]);
            acc[i][j] = fmaf(af[i].z, bf[j].z, acc[i][j]);
            acc[i][j] = fmaf(af[i].w, bf[j].w, acc[i][j]);
          }
      }
      __syncthreads();
    }

    // epilogue: score = t2[j] - 2*dot  (x2 and sqrt deferred: both monotonic)
#pragma unroll
    for (int j = 0; j < 4; ++j) {
      int jj = jbase + tx + 16 * j;
      if (jj < cend) {
        float t2v = t2g[jj];
#pragma unroll
        for (int i = 0; i < 4; ++i) {
          float sc = fmaf(-2.f, acc[i][j], t2v);
          if (lt_pair(sc, jj, tv[i][KTOP - 1], ti[i][KTOP - 1])) {
            tv[i][KTOP - 1] = sc; ti[i][KTOP - 1] = jj;
#pragma unroll
            for (int p = KTOP - 1; p > 0; --p) {
              if (lt_pair(tv[i][p], ti[i][p], tv[i][p - 1], ti[i][p - 1])) {
                float tf = tv[i][p]; tv[i][p] = tv[i][p - 1]; tv[i][p - 1] = tf;
                int tn = ti[i][p]; ti[i][p] = ti[i][p - 1]; ti[i][p - 1] = tn;
              }
            }
          }
        }
      }
    }
  }

  // merge the 16 tx-threads' sorted top-5 lists via shuffle tree (within wave)
#pragma unroll
  for (int i = 0; i < 4; ++i) {
#pragma unroll
    for (int delta = 8; delta >= 1; delta >>= 1) {
      float ov[KTOP]; int oi[KTOP];
#pragma unroll
      for (int s = 0; s < KTOP; ++s) {
        ov[s] = __shfl_down(tv[i][s], delta, 64);
        oi[s] = __shfl_down(ti[i][s], delta, 64);
      }
      float nv[KTOP]; int ni[KTOP];
#pragma unroll
      for (int s = 0; s < KTOP; ++s) {
        // k smallest of two sorted k-lists: elementwise min(a[s], b[k-1-s])
        if (lt_pair(tv[i][s], ti[i][s], ov[KTOP - 1 - s], oi[KTOP - 1 - s])) {
          nv[s] = tv[i][s]; ni[s] = ti[i][s];
        } else {
          nv[s] = ov[KTOP - 1 - s]; ni[s] = oi[KTOP - 1 - s];
        }
      }
      // bubble-sort network (static indices, stays in VGPRs)
#pragma unroll
      for (int a = 0; a < KTOP; ++a)
#pragma unroll
        for (int b = 0; b < KTOP - 1 - a; ++b) {
          if (lt_pair(nv[b + 1], ni[b + 1], nv[b], ni[b])) {
            float tf = nv[b]; nv[b] = nv[b + 1]; nv[b + 1] = tf;
            int tn = ni[b]; ni[b] = ni[b + 1]; ni[b + 1] = tn;
          }
        }
#pragma unroll
      for (int s = 0; s < KTOP; ++s) { tv[i][s] = nv[s]; ti[i][s] = ni[s]; }
    }
  }

  if (tx == 0) {
#pragma unroll
    for (int i = 0; i < 4; ++i) {
      int q = q0 + ty + 16 * i;
      size_t base = ((size_t)q * NCHUNK + blockIdx.y) * KTOP;
#pragma unroll
      for (int s = 0; s < KTOP; ++s) {
        pvals[base + s] = tv[i][s];
        pidx[base + s] = ti[i][s];
      }
    }
  }
}

// ---------------- final merge: 160 candidates -> 5, write all outputs ----------------
__global__ __launch_bounds__(256) void knn_merge(
    float* __restrict__ pvals, int* __restrict__ pidx,
    const float* __restrict__ x2, const int* __restrict__ labels,
    float* __restrict__ out) {
  int q = blockIdx.x * 256 + threadIdx.x;
  if (q >= NQ) return;
  const int M = NCHUNK * KTOP;  // 160
  size_t base = (size_t)q * M;
  float bv[KTOP]; int bi[KTOP];
#pragma unroll
  for (int s = 0; s < KTOP; ++s) {
    float best = FLT_MAX; int bestid = 0x7FFFFFFF; int bp = 0;
    for (int m = 0; m < M; ++m) {
      float v = pvals[base + m]; int id = pidx[base + m];
      if (v < best || (v == best && id < bestid)) { best = v; bestid = id; bp = m; }
    }
    pvals[base + bp] = FLT_MAX; pidx[base + bp] = 0x7FFFFFFF;
    bv[s] = best; bi[s] = bestid;
  }
  float xq = x2[q];
#pragma unroll
  for (int s = 0; s < KTOP; ++s) {
    float d2 = bv[s] + xq;
    d2 = d2 > 0.f ? d2 : 0.f;
    out[(size_t)q * KTOP + s] = sqrtf(d2);                       // topk_dists [Q,K]
    out[(size_t)NQ * KTOP + (size_t)q * KTOP + s] = (float)bi[s]; // topk_inds  [Q,K]
    out[(size_t)2 * NQ * KTOP + (size_t)s * NQ + q] =
        (float)labels[bi[s]];                                     // pred [K,Q]
  }
}

extern "C" void kernel_launch(void* const* d_in, const int* in_sizes, int n_in,
                              void* d_out, int out_size, void* d_ws, size_t ws_size,
                              hipStream_t stream) {
  const float* x = (const float*)d_in[0];
  const float* T = (const float*)d_in[1];
  const int* labels = (const int*)d_in[2];
  // d_in[3] is k == 5, compile-time KTOP
  float* out = (float*)d_out;
  char* ws = (char*)d_ws;

  float* t2 = (float*)ws;                          // NT floats  (400000 B)
  float* x2 = (float*)(ws + 400000);               // NQ floats  (8192 B)
  float* pvals = (float*)(ws + 409600);            // NQ*NCHUNK*KTOP floats (1310720 B)
  int* pidx = (int*)(ws + 409600 + 1310720);       // same count of ints

  int nwaves = NT + NQ;                            // 102048
  int nblocks = (nwaves + 3) / 4;                  // 4 waves (256 thr) per block
  norms_kernel<<<nblocks, 256, 0, stream>>>(x, T, t2, x2);

  dim3 grid(NQ / QT, NCHUNK);                      // 32 x 32
  knn_main<<<grid, 256, 0, stream>>>(x, T, t2, pvals, pidx);

  knn_merge<<<NQ / 256, 256, 0, stream>>>(pvals, pidx, x2, labels, out);
}

// Round 2
// 2129.070 us; speedup vs baseline: 2.1710x; 2.1710x over previous
//
#include <hip/hip_runtime.h>
#include <float.h>
#include <math.h>

#define NQ 2048
#define NT 100000
#define DIM 512
#define KTOP 5
#define QTILE 128          // queries per block
#define TTILE 128          // targets per t-tile
#define NTPC 12            // t-tiles per chunk
#define CHUNK (NTPC*TTILE) // 1536
#define NCH 66             // 66*1536 = 101376 >= 100000
#define BK 32

typedef float f32x4 __attribute__((ext_vector_type(4)));
typedef short s16x8 __attribute__((ext_vector_type(8)));
typedef unsigned int u32;

__device__ __forceinline__ bool lt_pair(float v1, int i1, float v2, int i2) {
  return v1 < v2 || (v1 == v2 && i1 < i2);
}

__device__ __forceinline__ void ins5(float* tv, int* tix, float sc, int idx) {
  if (lt_pair(sc, idx, tv[4], tix[4])) {
    tv[4] = sc; tix[4] = idx;
#pragma unroll
    for (int p = 4; p > 0; --p)
      if (lt_pair(tv[p], tix[p], tv[p - 1], tix[p - 1])) {
        float tf = tv[p]; tv[p] = tv[p - 1]; tv[p - 1] = tf;
        int tn = tix[p]; tix[p] = tix[p - 1]; tix[p - 1] = tn;
      }
  }
}

// merge sorted-5 (av,ai) with sorted-5 (bv,bi) -> sorted-5 into (av,ai)
__device__ __forceinline__ void merge5(float* av, int* ai, const float* bv, const int* bi) {
  float nv[5]; int ni[5];
#pragma unroll
  for (int s = 0; s < 5; ++s) {
    if (lt_pair(av[s], ai[s], bv[4 - s], bi[4 - s])) { nv[s] = av[s]; ni[s] = ai[s]; }
    else { nv[s] = bv[4 - s]; ni[s] = bi[4 - s]; }
  }
#pragma unroll
  for (int a = 0; a < 5; ++a)
#pragma unroll
    for (int b = 0; b < 4 - a; ++b)
      if (lt_pair(nv[b + 1], ni[b + 1], nv[b], ni[b])) {
        float tf = nv[b]; nv[b] = nv[b + 1]; nv[b + 1] = tf;
        int tn = ni[b]; ni[b] = ni[b + 1]; ni[b + 1] = tn;
      }
#pragma unroll
  for (int s = 0; s < 5; ++s) { av[s] = nv[s]; ai[s] = ni[s]; }
}

// fp32 -> (hi, mid) bf16 split for 8 consecutive floats
__device__ __forceinline__ void cvt8(const float* p, s16x8& hv, s16x8& mv) {
  f32x4 a = *(const f32x4*)p;
  f32x4 b = *(const f32x4*)(p + 4);
  float e[8] = {a[0], a[1], a[2], a[3], b[0], b[1], b[2], b[3]};
#pragma unroll
  for (int i = 0; i < 8; ++i) {
    u32 u = __builtin_bit_cast(u32, e[i]);
    u32 r = u + 0x7FFFu + ((u >> 16) & 1u);        // RNE to bf16
    u32 hib = r & 0xFFFF0000u;
    float resid = e[i] - __builtin_bit_cast(float, hib);
    u32 u2 = __builtin_bit_cast(u32, resid);
    u32 r2 = u2 + 0x7FFFu + ((u2 >> 16) & 1u);
    hv[i] = (short)(r >> 16);
    mv[i] = (short)(r2 >> 16);
  }
}

// ---------------- norms: t2[NT], x2[NQ] ----------------
__global__ __launch_bounds__(256) void norms_kernel(
    const float* __restrict__ x, const float* __restrict__ T,
    float* __restrict__ t2, float* __restrict__ x2) {
  int gid = blockIdx.x * 256 + threadIdx.x;
  int wave = gid >> 6;
  int lane = threadIdx.x & 63;
  if (wave >= NT + NQ) return;
  const float* row = (wave < NT) ? (T + (size_t)wave * DIM)
                                 : (x + (size_t)(wave - NT) * DIM);
  const float4* r4 = (const float4*)row;
  float4 a = r4[lane];
  float4 b = r4[lane + 64];
  float s = a.x*a.x + a.y*a.y + a.z*a.z + a.w*a.w
          + b.x*b.x + b.y*b.y + b.z*b.z + b.w*b.w;
#pragma unroll
  for (int off = 32; off > 0; off >>= 1) s += __shfl_down(s, off, 64);
  if (lane == 0) { if (wave < NT) t2[wave] = s; else x2[wave - NT] = s; }
}

// ---------------- main: bf16x3-split MFMA GEMM + fused top-5 ----------------
// LDS (shorts): A_hi [0,4096) A_mid [4096,8192) B_hi [8192,12288) B_mid [12288,16384)
// Fragment f (tile = f>>6, lane = f&63) lives at offset f*8 shorts (16B) — frag
// reads are lane-contiguous (conflict-free), staging is one ds_write_b128/frag.
__global__ __launch_bounds__(256) void knn_mfma(
    const float* __restrict__ x, const float* __restrict__ T,
    const float* __restrict__ t2g,
    float* __restrict__ pvals, int* __restrict__ pidx) {
  __shared__ short lds_s[16384];   // 32 KB

  const int tid = threadIdx.x;
  const int w = tid >> 6;
  const int l = tid & 63;
  const int q0 = blockIdx.x * QTILE;
  const int cbase = blockIdx.y * CHUNK;
  const int wr = (w >> 1) * 64;    // wave row base within block
  const int wc = (w & 1) * 64;     // wave col base within t-tile

  float tv[KTOP]; int tix[KTOP];
#pragma unroll
  for (int s = 0; s < KTOP; ++s) { tv[s] = FLT_MAX; tix[s] = 0x7FFFFFFF; }

  for (int tt = 0; tt < NTPC; ++tt) {
    const int jbase = cbase + tt * TTILE;
    f32x4 acc[4][4];
#pragma unroll
    for (int i = 0; i < 4; ++i)
#pragma unroll
      for (int j = 0; j < 4; ++j) acc[i][j] = (f32x4){0.f, 0.f, 0.f, 0.f};

    for (int kb = 0; kb < DIM; kb += BK) {
      __syncthreads();  // prior frag/epilogue reads done before overwrite
#pragma unroll
      for (int g = 0; g < 2; ++g) {
        int f = tid + g * 256;
        int m = f & 15, quad = (f >> 4) & 3, tile = f >> 6;
        {
          int row = q0 + tile * 16 + m;
          const float* p = x + (size_t)row * DIM + kb + quad * 8;
          s16x8 hv, mv; cvt8(p, hv, mv);
          *(s16x8*)(lds_s + f * 8) = hv;
          *(s16x8*)(lds_s + 4096 + f * 8) = mv;
        }
        {
          int jr = jbase + tile * 16 + m;
          int jc = jr < NT ? jr : NT - 1;
          const float* p = T + (size_t)jc * DIM + kb + quad * 8;
          s16x8 hv, mv; cvt8(p, hv, mv);
          *(s16x8*)(lds_s + 8192 + f * 8) = hv;
          *(s16x8*)(lds_s + 12288 + f * 8) = mv;
        }
      }
      __syncthreads();

      s16x8 ah[4], am[4];
      const int arow = wr >> 4;   // base a-tile index
#pragma unroll
      for (int i = 0; i < 4; ++i) {
        ah[i] = *(const s16x8*)(lds_s + ((arow + i) * 64 + l) * 8);
        am[i] = *(const s16x8*)(lds_s + 4096 + ((arow + i) * 64 + l) * 8);
      }
#pragma unroll
      for (int j = 0; j < 4; ++j) {
        int btile = (wc >> 4) + j;
        s16x8 bh = *(const s16x8*)(lds_s + 8192 + (btile * 64 + l) * 8);
        s16x8 bm = *(const s16x8*)(lds_s + 12288 + (btile * 64 + l) * 8);
#pragma unroll
        for (int i = 0; i < 4; ++i) {
          acc[i][j] = __builtin_amdgcn_mfma_f32_16x16x32_bf16(ah[i], bh, acc[i][j], 0, 0, 0);
          acc[i][j] = __builtin_amdgcn_mfma_f32_16x16x32_bf16(ah[i], bm, acc[i][j], 0, 0, 0);
          acc[i][j] = __builtin_amdgcn_mfma_f32_16x16x32_bf16(am[i], bh, acc[i][j], 0, 0, 0);
        }
      }
    }

    // epilogue: transpose C through wave-private LDS scratch so each lane
    // owns one query row; keep persistent per-lane top-5 (10 VGPRs).
    __syncthreads();  // all waves done with frag reads; staging LDS reusable
    float* scr = ((float*)lds_s) + w * 1280;  // 64 rows x 20 (stride pad)
#pragma unroll
    for (int jj = 0; jj < 4; ++jj) {
      int colg = jbase + wc + jj * 16 + (l & 15);
      int cc = colg < NT ? colg : NT - 1;
      float t2v = t2g[cc];
      bool valid = colg < NT;
#pragma unroll
      for (int i = 0; i < 4; ++i)
#pragma unroll
        for (int r = 0; r < 4; ++r) {
          // score = t2[j] - 2*dot  (x2 & sqrt deferred: monotonic per row)
          float sc = valid ? fmaf(-2.f, acc[i][jj][r], t2v) : FLT_MAX;
          int rowl = i * 16 + ((l >> 4) << 2) + r;
          scr[rowl * 20 + (l & 15)] = sc;
        }
      int cbg = jbase + wc + jj * 16;
#pragma unroll
      for (int c4 = 0; c4 < 4; ++c4) {
        f32x4 rv = *(const f32x4*)(scr + l * 20 + c4 * 4);
#pragma unroll
        for (int c = 0; c < 4; ++c) ins5(tv, tix, rv[c], cbg + c4 * 4 + c);
      }
    }
  }

  // cross-wave merge: waves (0,1) share rows 0-63, (2,3) share rows 64-127
  __syncthreads();
  float* ms = (float*)lds_s;
  int* msi = (int*)lds_s + 640;
  if (w & 1) {
    int rid = wr + l;
#pragma unroll
    for (int s = 0; s < KTOP; ++s) { ms[rid * 5 + s] = tv[s]; msi[rid * 5 + s] = tix[s]; }
  }
  __syncthreads();
  if (!(w & 1)) {
    int rid = wr + l;
    float ov[KTOP]; int oi[KTOP];
#pragma unroll
    for (int s = 0; s < KTOP; ++s) { ov[s] = ms[rid * 5 + s]; oi[s] = msi[rid * 5 + s]; }
    merge5(tv, tix, ov, oi);
    int q = q0 + rid;
    size_t base = ((size_t)q * NCH + blockIdx.y) * KTOP;
#pragma unroll
    for (int s = 0; s < KTOP; ++s) { pvals[base + s] = tv[s]; pidx[base + s] = tix[s]; }
  }
}

// ---------------- final merge: 330 candidates -> 5, write outputs ----------------
__global__ __launch_bounds__(256) void knn_merge(
    const float* __restrict__ pvals, const int* __restrict__ pidx,
    const float* __restrict__ x2, const int* __restrict__ labels,
    float* __restrict__ out) {
  int q = blockIdx.x * 256 + threadIdx.x;
  if (q >= NQ) return;
  float tv[KTOP]; int tix[KTOP];
#pragma unroll
  for (int s = 0; s < KTOP; ++s) { tv[s] = FLT_MAX; tix[s] = 0x7FFFFFFF; }
  size_t base = (size_t)q * NCH * KTOP;
  for (int m = 0; m < NCH * KTOP; ++m) ins5(tv, tix, pvals[base + m], pidx[base + m]);
  float xq = x2[q];
#pragma unroll
  for (int s = 0; s < KTOP; ++s) {
    float d2 = tv[s] + xq;
    d2 = d2 > 0.f ? d2 : 0.f;
    out[(size_t)q * KTOP + s] = sqrtf(d2);                        // topk_dists [Q,K]
    out[(size_t)NQ * KTOP + (size_t)q * KTOP + s] = (float)tix[s]; // topk_inds [Q,K]
    out[(size_t)2 * NQ * KTOP + (size_t)s * NQ + q] =
        (float)labels[tix[s]];                                     // pred [K,Q]
  }
}

extern "C" void kernel_launch(void* const* d_in, const int* in_sizes, int n_in,
                              void* d_out, int out_size, void* d_ws, size_t ws_size,
                              hipStream_t stream) {
  const float* x = (const float*)d_in[0];
  const float* T = (const float*)d_in[1];
  const int* labels = (const int*)d_in[2];
  float* out = (float*)d_out;
  char* ws = (char*)d_ws;

  float* t2 = (float*)ws;                        // 400000 B
  float* x2 = (float*)(ws + 400000);             // 8192 B (pad to 409600)
  float* pvals = (float*)(ws + 409600);          // 2048*66*5*4 = 2703360 B
  int* pidx = (int*)(ws + 409600 + 2703360);     // 2703360 B

  int nwaves = NT + NQ;
  int nblocks = (nwaves + 3) / 4;
  norms_kernel<<<nblocks, 256, 0, stream>>>(x, T, t2, x2);

  dim3 grid(NQ / QTILE, NCH);                    // 16 x 66
  knn_mfma<<<grid, 256, 0, stream>>>(x, T, t2, pvals, pidx);

  knn_merge<<<(NQ + 255) / 256, 256, 0, stream>>>(pvals, pidx, x2, labels, out);
}